// Round 15
// baseline (223.599 us; speedup 1.0000x reference)
//
#include <hip/hip_runtime.h>

// Pipeline: cvt(x,Wqkv,Wproj) -> GEMM qkv + fused bias/l2norm/scale/split (Q pre-scaled
//           smh*log2e) -> bias_prep (bf16 (bias-rowmax)*log2e) -> v_transpose (+k-perm) ->
//           flash attn (8 waves/block QBLK=128, KV-split x2, swapped-QK^T, bias C-init,
//                       in-register P, MFMA row-sum, reg-staged dbuf, 1 barrier/iter,
//                       launch_bounds(512,8), bijective XCD swizzle)
//           -> combine partials -> GEMM proj(f32+bias)
// B=2 L=2048 C=1024 H=16 D=64. All matmuls bf16 MFMA 16x16x32, f32 accumulate.

typedef __bf16 bf16x8 __attribute__((ext_vector_type(8)));
typedef __bf16 bf16x4 __attribute__((ext_vector_type(4)));
typedef float  f32x4  __attribute__((ext_vector_type(4)));

#define BB 2
#define LL 2048
#define CC 1024
#define HH 16
#define DD 64
#define LOG2E 1.44269504088896f

__device__ __forceinline__ f32x4 mfma_16x16x32(bf16x8 a, bf16x8 b, f32x4 c) {
    return __builtin_amdgcn_mfma_f32_16x16x32_bf16(a, b, c, 0, 0, 0);
}

// async global->LDS, 16B per lane; LDS dest = wave-uniform base + lane*16
__device__ __forceinline__ void gload_lds16(const __bf16* g, __bf16* lds) {
    __builtin_amdgcn_global_load_lds(
        (const __attribute__((address_space(1))) unsigned int*)g,
        (__attribute__((address_space(3))) unsigned int*)lds,
        16, 0, 0);
}

__device__ __forceinline__ unsigned pk_bf16(float a, float b) {
    unsigned short ua = __builtin_bit_cast(unsigned short, (__bf16)a);
    unsigned short ub = __builtin_bit_cast(unsigned short, (__bf16)b);
    return (unsigned)ua | ((unsigned)ub << 16);
}

// ---------------- f32 -> bf16 convert ----------------
__global__ __launch_bounds__(256) void cvt_bf16_kernel(const float* __restrict__ in,
                                                       __bf16* __restrict__ out, int n4) {
    int i = blockIdx.x * 256 + threadIdx.x;
    if (i >= n4) return;
    float4 v = reinterpret_cast<const float4*>(in)[i];
    bf16x4 o;
    o[0] = (__bf16)v.x; o[1] = (__bf16)v.y; o[2] = (__bf16)v.z; o[3] = (__bf16)v.w;
    reinterpret_cast<bf16x4*>(out)[i] = o;
}

// ---------------- bias prep: rowmax + bf16((bias - rowmax)*log2e) ----------------
__global__ __launch_bounds__(256) void bias_prep_kernel(const float* __restrict__ bias,
                                                        __bf16* __restrict__ bias_bf) {
    __shared__ float wmax[4];
    const int l = blockIdx.x, tid = threadIdx.x;
    const int w = tid >> 6;
    float4 a = reinterpret_cast<const float4*>(bias + (size_t)l * 2048)[tid];
    float4 b = reinterpret_cast<const float4*>(bias + (size_t)l * 2048 + 1024)[tid];
    float m = fmaxf(fmaxf(fmaxf(a.x, a.y), fmaxf(a.z, a.w)),
                    fmaxf(fmaxf(b.x, b.y), fmaxf(b.z, b.w)));
#pragma unroll
    for (int off = 1; off < 64; off <<= 1) m = fmaxf(m, __shfl_xor(m, off, 64));
    if ((tid & 63) == 0) wmax[w] = m;
    __syncthreads();
    float M = fmaxf(fmaxf(wmax[0], wmax[1]), fmaxf(wmax[2], wmax[3]));
    bf16x4 o0, o1;
    o0[0] = (__bf16)((a.x - M) * LOG2E); o0[1] = (__bf16)((a.y - M) * LOG2E);
    o0[2] = (__bf16)((a.z - M) * LOG2E); o0[3] = (__bf16)((a.w - M) * LOG2E);
    o1[0] = (__bf16)((b.x - M) * LOG2E); o1[1] = (__bf16)((b.y - M) * LOG2E);
    o1[2] = (__bf16)((b.z - M) * LOG2E); o1[3] = (__bf16)((b.w - M) * LOG2E);
    reinterpret_cast<bf16x4*>(bias_bf + (size_t)l * 2048)[tid] = o0;
    reinterpret_cast<bf16x4*>(bias_bf + (size_t)l * 2048 + 1024)[tid] = o1;
}

// ---------------- QKV GEMM + fused bias/l2norm/scale/split ----------------
__global__ __launch_bounds__(256) void gemm_qkv_fused_kernel(
    const __bf16* __restrict__ A, const __bf16* __restrict__ Bm,
    const float* __restrict__ q_bias, const float* __restrict__ v_bias,
    const float* __restrict__ scale_mul,
    __bf16* __restrict__ Qw, __bf16* __restrict__ Kw, __bf16* __restrict__ Vw) {
    __shared__ __bf16 As[128 * 64];   // LDS[row][c] = A[row][c ^ ((row&7)<<4)]  (byte view)
    __shared__ __bf16 Bs[128 * 64];
    const int tid = threadIdx.x;
    const int K = 1024;
    const int nwg = gridDim.x * gridDim.y;
    const int flat = blockIdx.y * gridDim.x + blockIdx.x;
    const int wg = (flat & 7) * (nwg >> 3) + (flat >> 3);
    const int m0 = (wg % gridDim.x) * 128, n0 = (wg / gridDim.x) * 128;
    const int w  = tid >> 6, l = tid & 63;
    const int wr = (w >> 1) * 64, wc = (w & 1) * 64;
    const int lr = l & 15, lg = l >> 4;
    const int rmask = (lr & 7) << 4;
    f32x4 acc[4][4] = {};
    const int lrow = l >> 3;
    const int celem = (((l & 7) ^ lrow) << 3);

    for (int kt = 0; kt < K; kt += 64) {
        __syncthreads();
#pragma unroll
        for (int i = 0; i < 4; ++i) {
            const int row = w * 32 + i * 8;
            gload_lds16(A + (size_t)(m0 + row + lrow) * K + kt + celem, &As[row * 64]);
            gload_lds16(Bm + (size_t)(n0 + row + lrow) * K + kt + celem, &Bs[row * 64]);
        }
        asm volatile("s_waitcnt vmcnt(0)" ::: "memory");
        __syncthreads();
#pragma unroll
        for (int kk = 0; kk < 2; ++kk) {
            bf16x8 af[4], bfr[4];
#pragma unroll
            for (int m = 0; m < 4; ++m)
                af[m] = *reinterpret_cast<const bf16x8*>(
                    (char*)As + (wr + m * 16 + lr) * 128 + ((kk * 64 + lg * 16) ^ rmask));
#pragma unroll
            for (int n = 0; n < 4; ++n)
                bfr[n] = *reinterpret_cast<const bf16x8*>(
                    (char*)Bs + (wc + n * 16 + lr) * 128 + ((kk * 64 + lg * 16) ^ rmask));
#pragma unroll
            for (int m = 0; m < 4; ++m)
#pragma unroll
                for (int n = 0; n < 4; ++n)
                    acc[m][n] = mfma_16x16x32(af[m], bfr[n], acc[m][n]);
        }
    }

    // ---- fused epilogue ----
    const int gcbase = n0 + wc;
    const int type = gcbase >> 10;           // 0=q, 1=k, 2=v
    const int h = (gcbase & 1023) >> 6;
    float qscale = 1.0f;
    if (type == 0) qscale = __expf(fminf(scale_mul[h], 4.60517019f)) * LOG2E;
    __bf16* dst = (type == 0) ? Qw : (type == 1) ? Kw : Vw;

#pragma unroll
    for (int m = 0; m < 4; ++m) {
        if (type != 1) {
            const float* bptr = (type == 0) ? q_bias : v_bias;
#pragma unroll
            for (int n = 0; n < 4; ++n) {
                float bv = bptr[(gcbase & 1023) + n * 16 + lr];
#pragma unroll
                for (int r = 0; r < 4; ++r) acc[m][n][r] += bv;
            }
        }
        float rs[4];
        if (type < 2) {
#pragma unroll
            for (int r = 0; r < 4; ++r) {
                float ss = 0.f;
#pragma unroll
                for (int n = 0; n < 4; ++n) ss += acc[m][n][r] * acc[m][n][r];
                rs[r] = ss;
            }
#pragma unroll
            for (int off = 1; off < 16; off <<= 1)
#pragma unroll
                for (int r = 0; r < 4; ++r) rs[r] += __shfl_xor(rs[r], off, 64);
#pragma unroll
            for (int r = 0; r < 4; ++r)
                rs[r] = ((type == 0) ? qscale : 1.0f) / fmaxf(sqrtf(rs[r]), 1e-12f);
        } else {
#pragma unroll
            for (int r = 0; r < 4; ++r) rs[r] = 1.0f;
        }
        const int rowg = m0 + wr + m * 16 + lg * 4;
#pragma unroll
        for (int n = 0; n < 4; ++n) {
            const int d = n * 16 + lr;
#pragma unroll
            for (int r = 0; r < 4; ++r) {
                const int row = rowg + r;
                const int bb = row >> 11, ll = row & 2047;
                dst[((size_t)((bb << 4) + h) * 2048 + ll) * 64 + d] =
                    (__bf16)(acc[m][n][r] * rs[r]);
            }
        }
    }
}

// ---------------- GEMM proj: C = A*B^T + bias (f32 out), m97 + XCD swz ----------
__global__ __launch_bounds__(256) void gemm_proj_kernel(
    const __bf16* __restrict__ A, const __bf16* __restrict__ Bm,
    float* __restrict__ Cf, const float* __restrict__ bias, int M, int N, int K) {
    __shared__ __bf16 As[128 * 64];
    __shared__ __bf16 Bs[128 * 64];
    const int tid = threadIdx.x;
    const int nwg = gridDim.x * gridDim.y;
    const int flat = blockIdx.y * gridDim.x + blockIdx.x;
    const int wg = (flat & 7) * (nwg >> 3) + (flat >> 3);
    const int m0 = (wg % gridDim.x) * 128, n0 = (wg / gridDim.x) * 128;
    const int w  = tid >> 6, l = tid & 63;
    const int wr = (w >> 1) * 64, wc = (w & 1) * 64;
    const int lr = l & 15, lg = l >> 4;
    const int rmask = (lr & 7) << 4;
    f32x4 acc[4][4] = {};
    const int lrow = l >> 3;
    const int celem = (((l & 7) ^ lrow) << 3);

    for (int kt = 0; kt < K; kt += 64) {
        __syncthreads();
#pragma unroll
        for (int i = 0; i < 4; ++i) {
            const int row = w * 32 + i * 8;
            gload_lds16(A + (size_t)(m0 + row + lrow) * K + kt + celem, &As[row * 64]);
            gload_lds16(Bm + (size_t)(n0 + row + lrow) * K + kt + celem, &Bs[row * 64]);
        }
        asm volatile("s_waitcnt vmcnt(0)" ::: "memory");
        __syncthreads();
#pragma unroll
        for (int kk = 0; kk < 2; ++kk) {
            bf16x8 af[4], bfr[4];
#pragma unroll
            for (int m = 0; m < 4; ++m)
                af[m] = *reinterpret_cast<const bf16x8*>(
                    (char*)As + (wr + m * 16 + lr) * 128 + ((kk * 64 + lg * 16) ^ rmask));
#pragma unroll
            for (int n = 0; n < 4; ++n)
                bfr[n] = *reinterpret_cast<const bf16x8*>(
                    (char*)Bs + (wc + n * 16 + lr) * 128 + ((kk * 64 + lg * 16) ^ rmask));
#pragma unroll
            for (int m = 0; m < 4; ++m)
#pragma unroll
                for (int n = 0; n < 4; ++n)
                    acc[m][n] = mfma_16x16x32(af[m], bfr[n], acc[m][n]);
        }
    }
#pragma unroll
    for (int m = 0; m < 4; ++m)
#pragma unroll
        for (int n = 0; n < 4; ++n) {
            const int row = m0 + wr + m * 16 + lg * 4;
            const int col = n0 + wc + n * 16 + lr;
#pragma unroll
            for (int r = 0; r < 4; ++r)
                Cf[(size_t)(row + r) * N + col] = acc[m][n][r] + bias[col];
        }
}

// ---------------- V transpose + k-permutation: (B,H,L,D) -> (B,H,D,perm(L)) ----------
// Within each 32-col block, col c' stores original k = 16*c'[2] + 4*c'[4:3] + c'[1:0],
// so attn's in-register P slot order matches contiguous b128 reads.
__global__ __launch_bounds__(256) void v_transpose_kernel(const __bf16* __restrict__ Vin,
                                                          __bf16* __restrict__ Vp) {
    __shared__ __bf16 T[64][72];
    const int lb = blockIdx.x, bh = blockIdx.y;
    const int tid = threadIdx.x;
    const size_t base = (size_t)bh * LL * DD;
    const int row = tid >> 2, c = (tid & 3) * 16;
    {
        const __bf16* src = Vin + base + (size_t)(lb * 64 + row) * 64 + c;
        *reinterpret_cast<bf16x8*>(&T[row][c])     = *reinterpret_cast<const bf16x8*>(src);
        *reinterpret_cast<bf16x8*>(&T[row][c + 8]) = *reinterpret_cast<const bf16x8*>(src + 8);
    }
    __syncthreads();
    __bf16 val[16];
#pragma unroll
    for (int jj = 0; jj < 16; ++jj) {
        const int cp = c + jj;
        const int wb = cp & 31;
        const int kloc = (cp & ~31) | (((wb >> 3) & 3) << 2) | (((wb >> 2) & 1) << 4) | (wb & 3);
        val[jj] = T[kloc][row];
    }
    __bf16* dst = Vp + base + (size_t)row * 2048 + lb * 64 + c;
    *reinterpret_cast<bf16x8*>(dst)     = *reinterpret_cast<bf16x8*>(&val[0]);
    *reinterpret_cast<bf16x8*>(dst + 8) = *reinterpret_cast<bf16x8*>(&val[8]);
}

// ---------------- flash attention: 8 waves (512 thr), QBLK=128, KV-split x2,
//                  launch_bounds(512,8) (4 blocks/CU), bijective XCD swizzle ----------
// grid 1024 flat; swz=(flat&7)*128+(flat>>3): each XCD serves 4 whole heads (K/V L2-local).
// bh = swz>>5, qb = (swz>>1)&15, sp = swz&1. Fixed-max softmax => partials add exactly.
__global__ __launch_bounds__(512, 8) void attn_kernel(
    const __bf16* __restrict__ Q, const __bf16* __restrict__ K,
    const __bf16* __restrict__ Vp, const __bf16* __restrict__ biasB,
    float* __restrict__ Of0, float* __restrict__ Of1, float* __restrict__ lsF) {
    __shared__ __bf16 KVs[2][2][64 * 64];   // [buf][K/V]; LDS[row][c]=G[row][c^((row&7)<<4)]
    const int flat = blockIdx.x;
    const int swz = (flat & 7) * 128 + (flat >> 3);
    const int bh = swz >> 5, qb = (swz >> 1) & 15, sp = swz & 1;
    const int tid = threadIdx.x;
    const int w = tid >> 6, l = tid & 63;
    const int lr = l & 15, lg = l >> 4;
    const int rmask = (lr & 7) << 4;
    const int b = bh >> 4, h = bh & 15;
    const size_t base = (size_t)bh * LL * DD;
    const int kb0 = sp * 16;

    const int gq = qb * 128 + w * 16 + lr;
    bf16x8 qf[2];
    qf[0] = *reinterpret_cast<const bf16x8*>(Q + base + (size_t)gq * 64 + lg * 8);
    qf[1] = *reinterpret_cast<const bf16x8*>(Q + base + (size_t)gq * 64 + 32 + lg * 8);
    const __bf16* brow = biasB + (size_t)gq * 2048 + lg * 4;

    bf16x8 ones;
#pragma unroll
    for (int j = 0; j < 8; ++j) ones[j] = (__bf16)1.0f;

    // staging: wave w covers rows [w*8, w*8+8); lane: row w*8+(l>>3), 8 elems at (l&7)*8
    const int srow = w * 8 + (l >> 3);
    const int sce  = (l & 7) * 8;                  // element col
    const int smask = (srow & 7) << 4;             // (l>>3)<<4
    const __bf16* kgbase = K  + base + (size_t)srow * 64   + sce;
    const __bf16* vgbase = Vp + base + (size_t)srow * 2048 + sce;

    bf16x8 k0, v0;
    auto stage_regs = [&](int kb) {
        k0 = *reinterpret_cast<const bf16x8*>(kgbase + (size_t)kb * 64 * 64);
        v0 = *reinterpret_cast<const bf16x8*>(vgbase + kb * 64);
    };
    auto write_lds = [&](int buf) {
        *reinterpret_cast<bf16x8*>((char*)KVs[buf][0] + srow * 128 + ((sce * 2) ^ smask)) = k0;
        *reinterpret_cast<bf16x8*>((char*)KVs[buf][1] + srow * 128 + ((sce * 2) ^ smask)) = v0;
    };

    stage_regs(kb0);
    write_lds(0);

    f32x4 Oa[4] = {};
    f32x4 ls = {};
    int cur = 0;

    bf16x4 bcur[4];
#pragma unroll
    for (int t = 0; t < 4; ++t)
        bcur[t] = *reinterpret_cast<const bf16x4*>(brow + kb0 * 64 + t * 16);

    for (int kb = 0; kb < 16; ++kb) {
        __syncthreads();                    // buf[cur] published; buf[cur^1] free
        if (kb < 15) stage_regs(kb0 + kb + 1);

        bf16x4 bnext[4];
        if (kb < 15) {
#pragma unroll
            for (int t = 0; t < 4; ++t)
                bnext[t] = *reinterpret_cast<const bf16x4*>(brow + (kb0 + kb + 1) * 64 + t * 16);
        }

        const char* Kc = (const char*)KVs[cur][0];
        const char* Vc = (const char*)KVs[cur][1];

        // acc init = bias'(bf16); no cexp (cancels in O = sum(pv)/sum(p))
        f32x4 sa[4];
#pragma unroll
        for (int t = 0; t < 4; ++t)
#pragma unroll
            for (int r = 0; r < 4; ++r)
                sa[t][r] = (float)bcur[t][r];

        // S^T·log2e + bias' : lane q=lr, k = 16t+4lg+r
#pragma unroll
        for (int t = 0; t < 4; ++t) {
            const char* kr = Kc + (t * 16 + lr) * 128;
            bf16x8 kf0 = *reinterpret_cast<const bf16x8*>(kr + ((lg * 16) ^ rmask));
            bf16x8 kf1 = *reinterpret_cast<const bf16x8*>(kr + ((64 + lg * 16) ^ rmask));
            sa[t] = mfma_16x16x32(kf0, qf[0], sa[t]);
            sa[t] = mfma_16x16x32(kf1, qf[1], sa[t]);
        }

        // softmax: p = exp2(sa); pack lane-local values into A-operand slots
        float p[4][4];
#pragma unroll
        for (int t = 0; t < 4; ++t)
#pragma unroll
            for (int r = 0; r < 4; ++r)
                p[t][r] = exp2f(sa[t][r]);
        union Upa { unsigned u[4]; bf16x8 v; } pa0, pa1;
        pa0.u[0] = pk_bf16(p[0][0], p[0][1]); pa0.u[1] = pk_bf16(p[0][2], p[0][3]);
        pa0.u[2] = pk_bf16(p[1][0], p[1][1]); pa0.u[3] = pk_bf16(p[1][2], p[1][3]);
        pa1.u[0] = pk_bf16(p[2][0], p[2][1]); pa1.u[1] = pk_bf16(p[2][2], p[2][3]);
        pa1.u[2] = pk_bf16(p[3][0], p[3][1]); pa1.u[3] = pk_bf16(p[3][2], p[3][3]);

        // row-sum via MFMA (B = ones): ls rows = Oa rows
        ls = mfma_16x16x32(pa0.v, ones, ls);
        ls = mfma_16x16x32(pa1.v, ones, ls);

        // O += P·V : V pre-permuted globally -> contiguous b128 reads (same pattern as K)
#pragma unroll
        for (int t = 0; t < 4; ++t) {
            const char* vr = Vc + (t * 16 + lr) * 128;
            bf16x8 vf0 = *reinterpret_cast<const bf16x8*>(vr + ((lg * 16) ^ rmask));
            bf16x8 vf1 = *reinterpret_cast<const bf16x8*>(vr + ((64 + lg * 16) ^ rmask));
            Oa[t] = mfma_16x16x32(pa0.v, vf0, Oa[t]);
            Oa[t] = mfma_16x16x32(pa1.v, vf1, Oa[t]);
        }

        if (kb < 15) {
            write_lds(cur ^ 1);             // write-late; dep on loads forces vmcnt
#pragma unroll
            for (int t = 0; t < 4; ++t) bcur[t] = bnext[t];
        }
        cur ^= 1;
    }

    // partial outputs (no normalization; combine pass divides)
    float* Ofp = sp ? Of1 : Of0;
#pragma unroll
    for (int t = 0; t < 4; ++t)
#pragma unroll
        for (int r = 0; r < 4; ++r) {
            const int row = qb * 128 + w * 16 + lg * 4 + r;
            Ofp[((size_t)(b * 2048 + row)) * 1024 + h * 64 + t * 16 + lr] = Oa[t][r];
        }
    if (lr == 0) {
#pragma unroll
        for (int r = 0; r < 4; ++r) {
            const int row = qb * 128 + w * 16 + lg * 4 + r;
            lsF[((size_t)sp * 32 + bh) * 2048 + row] = ls[r];
        }
    }
}

// ---------------- combine: Oc = (Of0 + Of1) / (ls0 + ls1), bf16 ----------------
__global__ __launch_bounds__(256) void combine_kernel(
    const float* __restrict__ Of0, const float* __restrict__ Of1,
    const float* __restrict__ lsF, __bf16* __restrict__ Oc) {
    const int i = blockIdx.x * 256 + threadIdx.x;  // f32x4 group, 1M total
    const int e = i * 4;
    const int row = e >> 10;                       // b*2048 + l
    const int col = e & 1023;
    const int h = col >> 6;
    const int b = row >> 11, l = row & 2047;
    const size_t lsi = ((size_t)(b * 16 + h)) * 2048 + l;
    const float inv = 1.0f / (lsF[lsi] + lsF[(size_t)32 * 2048 + lsi]);
    float4 a = reinterpret_cast<const float4*>(Of0)[i];
    float4 c = reinterpret_cast<const float4*>(Of1)[i];
    bf16x4 o;
    o[0] = (__bf16)((a.x + c.x) * inv);
    o[1] = (__bf16)((a.y + c.y) * inv);
    o[2] = (__bf16)((a.z + c.z) * inv);
    o[3] = (__bf16)((a.w + c.w) * inv);
    reinterpret_cast<bf16x4*>(Oc)[i] = o;
}

// ---------------- launch ----------------
extern "C" void kernel_launch(void* const* d_in, const int* in_sizes, int n_in,
                              void* d_out, int out_size, void* d_ws, size_t ws_size,
                              hipStream_t stream) {
    const float* x         = (const float*)d_in[0];
    const float* attn_bias = (const float*)d_in[1];
    const float* W_qkv     = (const float*)d_in[2];
    const float* q_bias    = (const float*)d_in[3];
    const float* v_bias    = (const float*)d_in[4];
    const float* scale_mul = (const float*)d_in[5];
    const float* W_proj    = (const float*)d_in[6];
    const float* b_proj    = (const float*)d_in[7];
    float* out = (float*)d_out;

    char* ws = (char*)d_ws;
    size_t off = 0;
    auto alloc = [&](size_t bytes) {
        void* p = ws + off;
        off = (off + bytes + 255) & ~(size_t)255;
        return p;
    };
    // Vw and xb first: both dead by attn time -> Of partial 0 aliases [0, 16MB)
    __bf16* Vw      = (__bf16*)alloc((size_t)BB * HH * LL * DD * 2);   //  8 MB (off 0)
    __bf16* xb      = (__bf16*)alloc((size_t)4096 * 1024 * 2);         //  8 MB (off 8M)
    __bf16* wqkvb   = (__bf16*)alloc((size_t)3072 * 1024 * 2);         //  6 MB
    __bf16* wprojb  = (__bf16*)alloc((size_t)1024 * 1024 * 2);         //  2 MB
    __bf16* Qw      = (__bf16*)alloc((size_t)BB * HH * LL * DD * 2);   //  8 MB
    __bf16* Kw      = (__bf16*)alloc((size_t)BB * HH * LL * DD * 2);   //  8 MB
    __bf16* Oc      = (__bf16*)alloc((size_t)4096 * 1024 * 2);         //  8 MB
    __bf16* biasB   = (__bf16*)alloc((size_t)2048 * 2048 * 2);         //  8 MB
    __bf16* Vp      = (__bf16*)alloc((size_t)BB * HH * LL * DD * 2);   //  8 MB
    float*  Of1     = (float*)alloc((size_t)4096 * 1024 * 4);          // 16 MB (split 1)
    float*  lsF     = (float*)alloc((size_t)2 * 32 * 2048 * 4);        // 0.5 MB
    float*  Of0     = (float*)d_ws;   // split 0 aliases Vw+xb (both dead at attn time)

    cvt_bf16_kernel<<<4096, 256, 0, stream>>>(x, xb, 4096 * 1024 / 4);
    cvt_bf16_kernel<<<3072, 256, 0, stream>>>(W_qkv, wqkvb, 3072 * 1024 / 4);
    cvt_bf16_kernel<<<1024, 256, 0, stream>>>(W_proj, wprojb, 1024 * 1024 / 4);

    gemm_qkv_fused_kernel<<<dim3(32, 24), 256, 0, stream>>>(
        xb, wqkvb, q_bias, v_bias, scale_mul, Qw, Kw, Vw);

    bias_prep_kernel<<<2048, 256, 0, stream>>>(attn_bias, biasB);
    v_transpose_kernel<<<dim3(32, 32), 256, 0, stream>>>(Vw, Vp);

    attn_kernel<<<1024, 512, 0, stream>>>(Qw, Kw, Vp, biasB, Of0, Of1, lsF);

    combine_kernel<<<4096, 256, 0, stream>>>(Of0, Of1, lsF, Oc);

    gemm_proj_kernel<<<dim3(32, 8), 256, 0, stream>>>(
        Oc, wprojb, out, b_proj, 4096, 1024, 1024);
}

// Round 16
// 179.645 us; speedup vs baseline: 1.2447x; 1.2447x over previous
//
#include <hip/hip_runtime.h>

// Pipeline: cvt3(x,Wqkv,Wproj in one launch) -> GEMM qkv + fused bias/l2norm/scale/split ->
//           prep (bias_prep + v_transpose(+k-perm) in one launch) ->
//           flash attn (R14-exact: 8 waves QBLK=128, KV-split x2, (512,6), natural grid)
//           -> combine partials -> GEMM proj(f32+bias)
// B=2 L=2048 C=1024 H=16 D=64. All matmuls bf16 MFMA 16x16x32, f32 accumulate.

typedef __bf16 bf16x8 __attribute__((ext_vector_type(8)));
typedef __bf16 bf16x4 __attribute__((ext_vector_type(4)));
typedef float  f32x4  __attribute__((ext_vector_type(4)));

#define BB 2
#define LL 2048
#define CC 1024
#define HH 16
#define DD 64
#define LOG2E 1.44269504088896f

__device__ __forceinline__ f32x4 mfma_16x16x32(bf16x8 a, bf16x8 b, f32x4 c) {
    return __builtin_amdgcn_mfma_f32_16x16x32_bf16(a, b, c, 0, 0, 0);
}

// async global->LDS, 16B per lane; LDS dest = wave-uniform base + lane*16
__device__ __forceinline__ void gload_lds16(const __bf16* g, __bf16* lds) {
    __builtin_amdgcn_global_load_lds(
        (const __attribute__((address_space(1))) unsigned int*)g,
        (__attribute__((address_space(3))) unsigned int*)lds,
        16, 0, 0);
}

__device__ __forceinline__ unsigned pk_bf16(float a, float b) {
    unsigned short ua = __builtin_bit_cast(unsigned short, (__bf16)a);
    unsigned short ub = __builtin_bit_cast(unsigned short, (__bf16)b);
    return (unsigned)ua | ((unsigned)ub << 16);
}

// ---------------- merged f32 -> bf16 convert (x, W_qkv, W_proj in one launch) ------------
__global__ __launch_bounds__(256) void cvt3_kernel(
    const float* __restrict__ x, const float* __restrict__ wq, const float* __restrict__ wp,
    __bf16* __restrict__ xb, __bf16* __restrict__ wqb, __bf16* __restrict__ wpb) {
    const int i = blockIdx.x * 256 + threadIdx.x;   // f32x4 index, 2097152 total
    const float* src; __bf16* dst; int off;
    if (i < 1048576)      { src = x;  dst = xb;  off = i; }
    else if (i < 1835008) { src = wq; dst = wqb; off = i - 1048576; }
    else                  { src = wp; dst = wpb; off = i - 1835008; }
    float4 v = reinterpret_cast<const float4*>(src)[off];
    bf16x4 o;
    o[0] = (__bf16)v.x; o[1] = (__bf16)v.y; o[2] = (__bf16)v.z; o[3] = (__bf16)v.w;
    reinterpret_cast<bf16x4*>(dst)[off] = o;
}

// ---------------- QKV GEMM + fused bias/l2norm/scale/split ----------------
__global__ __launch_bounds__(256) void gemm_qkv_fused_kernel(
    const __bf16* __restrict__ A, const __bf16* __restrict__ Bm,
    const float* __restrict__ q_bias, const float* __restrict__ v_bias,
    const float* __restrict__ scale_mul,
    __bf16* __restrict__ Qw, __bf16* __restrict__ Kw, __bf16* __restrict__ Vw) {
    __shared__ __bf16 As[128 * 64];   // LDS[row][c] = A[row][c ^ ((row&7)<<4)]  (byte view)
    __shared__ __bf16 Bs[128 * 64];
    const int tid = threadIdx.x;
    const int K = 1024;
    const int nwg = gridDim.x * gridDim.y;
    const int flat = blockIdx.y * gridDim.x + blockIdx.x;
    const int wg = (flat & 7) * (nwg >> 3) + (flat >> 3);
    const int m0 = (wg % gridDim.x) * 128, n0 = (wg / gridDim.x) * 128;
    const int w  = tid >> 6, l = tid & 63;
    const int wr = (w >> 1) * 64, wc = (w & 1) * 64;
    const int lr = l & 15, lg = l >> 4;
    const int rmask = (lr & 7) << 4;
    f32x4 acc[4][4] = {};
    const int lrow = l >> 3;
    const int celem = (((l & 7) ^ lrow) << 3);

    for (int kt = 0; kt < K; kt += 64) {
        __syncthreads();
#pragma unroll
        for (int i = 0; i < 4; ++i) {
            const int row = w * 32 + i * 8;
            gload_lds16(A + (size_t)(m0 + row + lrow) * K + kt + celem, &As[row * 64]);
            gload_lds16(Bm + (size_t)(n0 + row + lrow) * K + kt + celem, &Bs[row * 64]);
        }
        asm volatile("s_waitcnt vmcnt(0)" ::: "memory");
        __syncthreads();
#pragma unroll
        for (int kk = 0; kk < 2; ++kk) {
            bf16x8 af[4], bfr[4];
#pragma unroll
            for (int m = 0; m < 4; ++m)
                af[m] = *reinterpret_cast<const bf16x8*>(
                    (char*)As + (wr + m * 16 + lr) * 128 + ((kk * 64 + lg * 16) ^ rmask));
#pragma unroll
            for (int n = 0; n < 4; ++n)
                bfr[n] = *reinterpret_cast<const bf16x8*>(
                    (char*)Bs + (wc + n * 16 + lr) * 128 + ((kk * 64 + lg * 16) ^ rmask));
#pragma unroll
            for (int m = 0; m < 4; ++m)
#pragma unroll
                for (int n = 0; n < 4; ++n)
                    acc[m][n] = mfma_16x16x32(af[m], bfr[n], acc[m][n]);
        }
    }

    // ---- fused epilogue ----
    const int gcbase = n0 + wc;
    const int type = gcbase >> 10;           // 0=q, 1=k, 2=v
    const int h = (gcbase & 1023) >> 6;
    float qscale = 1.0f;
    if (type == 0) qscale = __expf(fminf(scale_mul[h], 4.60517019f)) * LOG2E;
    __bf16* dst = (type == 0) ? Qw : (type == 1) ? Kw : Vw;

#pragma unroll
    for (int m = 0; m < 4; ++m) {
        if (type != 1) {
            const float* bptr = (type == 0) ? q_bias : v_bias;
#pragma unroll
            for (int n = 0; n < 4; ++n) {
                float bv = bptr[(gcbase & 1023) + n * 16 + lr];
#pragma unroll
                for (int r = 0; r < 4; ++r) acc[m][n][r] += bv;
            }
        }
        float rs[4];
        if (type < 2) {
#pragma unroll
            for (int r = 0; r < 4; ++r) {
                float ss = 0.f;
#pragma unroll
                for (int n = 0; n < 4; ++n) ss += acc[m][n][r] * acc[m][n][r];
                rs[r] = ss;
            }
#pragma unroll
            for (int off = 1; off < 16; off <<= 1)
#pragma unroll
                for (int r = 0; r < 4; ++r) rs[r] += __shfl_xor(rs[r], off, 64);
#pragma unroll
            for (int r = 0; r < 4; ++r)
                rs[r] = ((type == 0) ? qscale : 1.0f) / fmaxf(sqrtf(rs[r]), 1e-12f);
        } else {
#pragma unroll
            for (int r = 0; r < 4; ++r) rs[r] = 1.0f;
        }
        const int rowg = m0 + wr + m * 16 + lg * 4;
#pragma unroll
        for (int n = 0; n < 4; ++n) {
            const int d = n * 16 + lr;
#pragma unroll
            for (int r = 0; r < 4; ++r) {
                const int row = rowg + r;
                const int bb = row >> 11, ll = row & 2047;
                dst[((size_t)((bb << 4) + h) * 2048 + ll) * 64 + d] =
                    (__bf16)(acc[m][n][r] * rs[r]);
            }
        }
    }
}

// ---------------- GEMM proj: C = A*B^T + bias (f32 out), m97 + XCD swz ----------
__global__ __launch_bounds__(256) void gemm_proj_kernel(
    const __bf16* __restrict__ A, const __bf16* __restrict__ Bm,
    float* __restrict__ Cf, const float* __restrict__ bias, int M, int N, int K) {
    __shared__ __bf16 As[128 * 64];
    __shared__ __bf16 Bs[128 * 64];
    const int tid = threadIdx.x;
    const int nwg = gridDim.x * gridDim.y;
    const int flat = blockIdx.y * gridDim.x + blockIdx.x;
    const int wg = (flat & 7) * (nwg >> 3) + (flat >> 3);
    const int m0 = (wg % gridDim.x) * 128, n0 = (wg / gridDim.x) * 128;
    const int w  = tid >> 6, l = tid & 63;
    const int wr = (w >> 1) * 64, wc = (w & 1) * 64;
    const int lr = l & 15, lg = l >> 4;
    const int rmask = (lr & 7) << 4;
    f32x4 acc[4][4] = {};
    const int lrow = l >> 3;
    const int celem = (((l & 7) ^ lrow) << 3);

    for (int kt = 0; kt < K; kt += 64) {
        __syncthreads();
#pragma unroll
        for (int i = 0; i < 4; ++i) {
            const int row = w * 32 + i * 8;
            gload_lds16(A + (size_t)(m0 + row + lrow) * K + kt + celem, &As[row * 64]);
            gload_lds16(Bm + (size_t)(n0 + row + lrow) * K + kt + celem, &Bs[row * 64]);
        }
        asm volatile("s_waitcnt vmcnt(0)" ::: "memory");
        __syncthreads();
#pragma unroll
        for (int kk = 0; kk < 2; ++kk) {
            bf16x8 af[4], bfr[4];
#pragma unroll
            for (int m = 0; m < 4; ++m)
                af[m] = *reinterpret_cast<const bf16x8*>(
                    (char*)As + (wr + m * 16 + lr) * 128 + ((kk * 64 + lg * 16) ^ rmask));
#pragma unroll
            for (int n = 0; n < 4; ++n)
                bfr[n] = *reinterpret_cast<const bf16x8*>(
                    (char*)Bs + (wc + n * 16 + lr) * 128 + ((kk * 64 + lg * 16) ^ rmask));
#pragma unroll
            for (int m = 0; m < 4; ++m)
#pragma unroll
                for (int n = 0; n < 4; ++n)
                    acc[m][n] = mfma_16x16x32(af[m], bfr[n], acc[m][n]);
        }
    }
#pragma unroll
    for (int m = 0; m < 4; ++m)
#pragma unroll
        for (int n = 0; n < 4; ++n) {
            const int row = m0 + wr + m * 16 + lg * 4;
            const int col = n0 + wc + n * 16 + lr;
#pragma unroll
            for (int r = 0; r < 4; ++r)
                Cf[(size_t)(row + r) * N + col] = acc[m][n][r] + bias[col];
        }
}

// ---------------- merged prep: bias_prep (blocks 0..2047) + v_transpose (2048..3071) ------
// bias_prep: rowmax + bf16((bias-rowmax)*log2e).
// v_transpose: (B,H,L,D)->(B,H,D,perm(L)); within each 32-col block, col c' stores
// original k = 16*c'[2] + 4*c'[4:3] + c'[1:0] (matches attn's in-register P slot order).
__global__ __launch_bounds__(256) void prep_kernel(
    const float* __restrict__ bias, __bf16* __restrict__ bias_bf,
    const __bf16* __restrict__ Vin, __bf16* __restrict__ Vp) {
    const int tid = threadIdx.x;
    if (blockIdx.x < 2048) {
        __shared__ float wmax[4];
        const int l = blockIdx.x;
        const int w = tid >> 6;
        float4 a = reinterpret_cast<const float4*>(bias + (size_t)l * 2048)[tid];
        float4 b = reinterpret_cast<const float4*>(bias + (size_t)l * 2048 + 1024)[tid];
        float m = fmaxf(fmaxf(fmaxf(a.x, a.y), fmaxf(a.z, a.w)),
                        fmaxf(fmaxf(b.x, b.y), fmaxf(b.z, b.w)));
#pragma unroll
        for (int off = 1; off < 64; off <<= 1) m = fmaxf(m, __shfl_xor(m, off, 64));
        if ((tid & 63) == 0) wmax[w] = m;
        __syncthreads();
        float M = fmaxf(fmaxf(wmax[0], wmax[1]), fmaxf(wmax[2], wmax[3]));
        bf16x4 o0, o1;
        o0[0] = (__bf16)((a.x - M) * LOG2E); o0[1] = (__bf16)((a.y - M) * LOG2E);
        o0[2] = (__bf16)((a.z - M) * LOG2E); o0[3] = (__bf16)((a.w - M) * LOG2E);
        o1[0] = (__bf16)((b.x - M) * LOG2E); o1[1] = (__bf16)((b.y - M) * LOG2E);
        o1[2] = (__bf16)((b.z - M) * LOG2E); o1[3] = (__bf16)((b.w - M) * LOG2E);
        reinterpret_cast<bf16x4*>(bias_bf + (size_t)l * 2048)[tid] = o0;
        reinterpret_cast<bf16x4*>(bias_bf + (size_t)l * 2048 + 1024)[tid] = o1;
    } else {
        __shared__ __bf16 T[64][72];
        const int idx = blockIdx.x - 2048;
        const int lb = idx & 31, bh = idx >> 5;
        const size_t base = (size_t)bh * LL * DD;
        const int row = tid >> 2, c = (tid & 3) * 16;
        {
            const __bf16* src = Vin + base + (size_t)(lb * 64 + row) * 64 + c;
            *reinterpret_cast<bf16x8*>(&T[row][c])     = *reinterpret_cast<const bf16x8*>(src);
            *reinterpret_cast<bf16x8*>(&T[row][c + 8]) = *reinterpret_cast<const bf16x8*>(src + 8);
        }
        __syncthreads();
        __bf16 val[16];
#pragma unroll
        for (int jj = 0; jj < 16; ++jj) {
            const int cp = c + jj;
            const int wb = cp & 31;
            const int kloc = (cp & ~31) | (((wb >> 3) & 3) << 2) | (((wb >> 2) & 1) << 4) | (wb & 3);
            val[jj] = T[kloc][row];
        }
        __bf16* dst = Vp + base + (size_t)row * 2048 + lb * 64 + c;
        *reinterpret_cast<bf16x8*>(dst)     = *reinterpret_cast<bf16x8*>(&val[0]);
        *reinterpret_cast<bf16x8*>(dst + 8) = *reinterpret_cast<bf16x8*>(&val[8]);
    }
}

// ---------------- flash attention: R14-exact. 8 waves (512 thr), QBLK=128, KV-split x2 ----
// grid (bh=32, qb=16, sp=2); wave w owns q-rows [qb*128+w*16, +16); each split covers
// 16 kb-tiles. Fixed-max softmax (no per-split max) => partials combine by pure addition.
// NOTE: (512,6) + natural bh-fastest dispatch order is load-bearing: ~2 blocks/CU residency
// keeps same-qb blocks temporally adjacent so the 8MB bias stays L2-resident (R15 lesson).
__global__ __launch_bounds__(512, 6) void attn_kernel(
    const __bf16* __restrict__ Q, const __bf16* __restrict__ K,
    const __bf16* __restrict__ Vp, const __bf16* __restrict__ biasB,
    float* __restrict__ Of0, float* __restrict__ Of1, float* __restrict__ lsF) {
    __shared__ __bf16 KVs[2][2][64 * 64];   // [buf][K/V]; LDS[row][c]=G[row][c^((row&7)<<4)]
    const int bh = blockIdx.x, qb = blockIdx.y, sp = blockIdx.z;
    const int tid = threadIdx.x;
    const int w = tid >> 6, l = tid & 63;
    const int lr = l & 15, lg = l >> 4;
    const int rmask = (lr & 7) << 4;
    const int b = bh >> 4, h = bh & 15;
    const size_t base = (size_t)bh * LL * DD;
    const int kb0 = sp * 16;

    const int gq = qb * 128 + w * 16 + lr;
    bf16x8 qf[2];
    qf[0] = *reinterpret_cast<const bf16x8*>(Q + base + (size_t)gq * 64 + lg * 8);
    qf[1] = *reinterpret_cast<const bf16x8*>(Q + base + (size_t)gq * 64 + 32 + lg * 8);
    const __bf16* brow = biasB + (size_t)gq * 2048 + lg * 4;

    bf16x8 ones;
#pragma unroll
    for (int j = 0; j < 8; ++j) ones[j] = (__bf16)1.0f;

    // staging: wave w covers rows [w*8, w*8+8); lane: row w*8+(l>>3), 8 elems at (l&7)*8
    const int srow = w * 8 + (l >> 3);
    const int sce  = (l & 7) * 8;                  // element col
    const int smask = (srow & 7) << 4;             // (l>>3)<<4
    const __bf16* kgbase = K  + base + (size_t)srow * 64   + sce;
    const __bf16* vgbase = Vp + base + (size_t)srow * 2048 + sce;

    bf16x8 k0, v0;
    auto stage_regs = [&](int kb) {
        k0 = *reinterpret_cast<const bf16x8*>(kgbase + (size_t)kb * 64 * 64);
        v0 = *reinterpret_cast<const bf16x8*>(vgbase + kb * 64);
    };
    auto write_lds = [&](int buf) {
        *reinterpret_cast<bf16x8*>((char*)KVs[buf][0] + srow * 128 + ((sce * 2) ^ smask)) = k0;
        *reinterpret_cast<bf16x8*>((char*)KVs[buf][1] + srow * 128 + ((sce * 2) ^ smask)) = v0;
    };

    stage_regs(kb0);
    write_lds(0);

    f32x4 Oa[4] = {};
    f32x4 ls = {};
    int cur = 0;

    bf16x4 bcur[4];
#pragma unroll
    for (int t = 0; t < 4; ++t)
        bcur[t] = *reinterpret_cast<const bf16x4*>(brow + kb0 * 64 + t * 16);

    for (int kb = 0; kb < 16; ++kb) {
        __syncthreads();                    // buf[cur] published; buf[cur^1] free
        if (kb < 15) stage_regs(kb0 + kb + 1);

        bf16x4 bnext[4];
        if (kb < 15) {
#pragma unroll
            for (int t = 0; t < 4; ++t)
                bnext[t] = *reinterpret_cast<const bf16x4*>(brow + (kb0 + kb + 1) * 64 + t * 16);
        }

        const char* Kc = (const char*)KVs[cur][0];
        const char* Vc = (const char*)KVs[cur][1];

        // acc init = bias'(bf16); no cexp (cancels in O = sum(pv)/sum(p))
        f32x4 sa[4];
#pragma unroll
        for (int t = 0; t < 4; ++t)
#pragma unroll
            for (int r = 0; r < 4; ++r)
                sa[t][r] = (float)bcur[t][r];

        // S^T·log2e + bias' : lane q=lr, k = 16t+4lg+r
#pragma unroll
        for (int t = 0; t < 4; ++t) {
            const char* kr = Kc + (t * 16 + lr) * 128;
            bf16x8 kf0 = *reinterpret_cast<const bf16x8*>(kr + ((lg * 16) ^ rmask));
            bf16x8 kf1 = *reinterpret_cast<const bf16x8*>(kr + ((64 + lg * 16) ^ rmask));
            sa[t] = mfma_16x16x32(kf0, qf[0], sa[t]);
            sa[t] = mfma_16x16x32(kf1, qf[1], sa[t]);
        }

        // softmax: p = exp2(sa); pack lane-local values into A-operand slots
        float p[4][4];
#pragma unroll
        for (int t = 0; t < 4; ++t)
#pragma unroll
            for (int r = 0; r < 4; ++r)
                p[t][r] = exp2f(sa[t][r]);
        union Upa { unsigned u[4]; bf16x8 v; } pa0, pa1;
        pa0.u[0] = pk_bf16(p[0][0], p[0][1]); pa0.u[1] = pk_bf16(p[0][2], p[0][3]);
        pa0.u[2] = pk_bf16(p[1][0], p[1][1]); pa0.u[3] = pk_bf16(p[1][2], p[1][3]);
        pa1.u[0] = pk_bf16(p[2][0], p[2][1]); pa1.u[1] = pk_bf16(p[2][2], p[2][3]);
        pa1.u[2] = pk_bf16(p[3][0], p[3][1]); pa1.u[3] = pk_bf16(p[3][2], p[3][3]);

        // row-sum via MFMA (B = ones): ls rows = Oa rows
        ls = mfma_16x16x32(pa0.v, ones, ls);
        ls = mfma_16x16x32(pa1.v, ones, ls);

        // O += P·V : V pre-permuted globally -> contiguous b128 reads (same pattern as K)
#pragma unroll
        for (int t = 0; t < 4; ++t) {
            const char* vr = Vc + (t * 16 + lr) * 128;
            bf16x8 vf0 = *reinterpret_cast<const bf16x8*>(vr + ((lg * 16) ^ rmask));
            bf16x8 vf1 = *reinterpret_cast<const bf16x8*>(vr + ((64 + lg * 16) ^ rmask));
            Oa[t] = mfma_16x16x32(pa0.v, vf0, Oa[t]);
            Oa[t] = mfma_16x16x32(pa1.v, vf1, Oa[t]);
        }

        if (kb < 15) {
            write_lds(cur ^ 1);             // write-late; dep on loads forces vmcnt
#pragma unroll
            for (int t = 0; t < 4; ++t) bcur[t] = bnext[t];
        }
        cur ^= 1;
    }

    // partial outputs (no normalization; combine pass divides)
    float* Ofp = sp ? Of1 : Of0;
#pragma unroll
    for (int t = 0; t < 4; ++t)
#pragma unroll
        for (int r = 0; r < 4; ++r) {
            const int row = qb * 128 + w * 16 + lg * 4 + r;
            Ofp[((size_t)(b * 2048 + row)) * 1024 + h * 64 + t * 16 + lr] = Oa[t][r];
        }
    if (lr == 0) {
#pragma unroll
        for (int r = 0; r < 4; ++r) {
            const int row = qb * 128 + w * 16 + lg * 4 + r;
            lsF[((size_t)sp * 32 + bh) * 2048 + row] = ls[r];
        }
    }
}

// ---------------- combine: Oc = (Of0 + Of1) / (ls0 + ls1), bf16 ----------------
__global__ __launch_bounds__(256) void combine_kernel(
    const float* __restrict__ Of0, const float* __restrict__ Of1,
    const float* __restrict__ lsF, __bf16* __restrict__ Oc) {
    const int i = blockIdx.x * 256 + threadIdx.x;  // f32x4 group, 1M total
    const int e = i * 4;
    const int row = e >> 10;                       // b*2048 + l
    const int col = e & 1023;
    const int h = col >> 6;
    const int b = row >> 11, l = row & 2047;
    const size_t lsi = ((size_t)(b * 16 + h)) * 2048 + l;
    const float inv = 1.0f / (lsF[lsi] + lsF[(size_t)32 * 2048 + lsi]);
    float4 a = reinterpret_cast<const float4*>(Of0)[i];
    float4 c = reinterpret_cast<const float4*>(Of1)[i];
    bf16x4 o;
    o[0] = (__bf16)((a.x + c.x) * inv);
    o[1] = (__bf16)((a.y + c.y) * inv);
    o[2] = (__bf16)((a.z + c.z) * inv);
    o[3] = (__bf16)((a.w + c.w) * inv);
    reinterpret_cast<bf16x4*>(Oc)[i] = o;
}

// ---------------- launch ----------------
extern "C" void kernel_launch(void* const* d_in, const int* in_sizes, int n_in,
                              void* d_out, int out_size, void* d_ws, size_t ws_size,
                              hipStream_t stream) {
    const float* x         = (const float*)d_in[0];
    const float* attn_bias = (const float*)d_in[1];
    const float* W_qkv     = (const float*)d_in[2];
    const float* q_bias    = (const float*)d_in[3];
    const float* v_bias    = (const float*)d_in[4];
    const float* scale_mul = (const float*)d_in[5];
    const float* W_proj    = (const float*)d_in[6];
    const float* b_proj    = (const float*)d_in[7];
    float* out = (float*)d_out;

    char* ws = (char*)d_ws;
    size_t off = 0;
    auto alloc = [&](size_t bytes) {
        void* p = ws + off;
        off = (off + bytes + 255) & ~(size_t)255;
        return p;
    };
    // Vw and xb first: both dead by attn time -> Of partial 0 aliases [0, 16MB)
    __bf16* Vw      = (__bf16*)alloc((size_t)BB * HH * LL * DD * 2);   //  8 MB (off 0)
    __bf16* xb      = (__bf16*)alloc((size_t)4096 * 1024 * 2);         //  8 MB (off 8M)
    __bf16* wqkvb   = (__bf16*)alloc((size_t)3072 * 1024 * 2);         //  6 MB
    __bf16* wprojb  = (__bf16*)alloc((size_t)1024 * 1024 * 2);         //  2 MB
    __bf16* Qw      = (__bf16*)alloc((size_t)BB * HH * LL * DD * 2);   //  8 MB
    __bf16* Kw      = (__bf16*)alloc((size_t)BB * HH * LL * DD * 2);   //  8 MB
    __bf16* Oc      = (__bf16*)alloc((size_t)4096 * 1024 * 2);         //  8 MB
    __bf16* biasB   = (__bf16*)alloc((size_t)2048 * 2048 * 2);         //  8 MB
    __bf16* Vp      = (__bf16*)alloc((size_t)BB * HH * LL * DD * 2);   //  8 MB
    float*  Of1     = (float*)alloc((size_t)4096 * 1024 * 4);          // 16 MB (split 1)
    float*  lsF     = (float*)alloc((size_t)2 * 32 * 2048 * 4);        // 0.5 MB
    float*  Of0     = (float*)d_ws;   // split 0 aliases Vw+xb (both dead at attn time)

    cvt3_kernel<<<8192, 256, 0, stream>>>(x, W_qkv, W_proj, xb, wqkvb, wprojb);

    gemm_qkv_fused_kernel<<<dim3(32, 24), 256, 0, stream>>>(
        xb, wqkvb, q_bias, v_bias, scale_mul, Qw, Kw, Vw);

    prep_kernel<<<3072, 256, 0, stream>>>(attn_bias, biasB, Vw, Vp);

    attn_kernel<<<dim3(32, 16, 2), 512, 0, stream>>>(Qw, Kw, Vp, biasB, Of0, Of1, lsF);

    combine_kernel<<<4096, 256, 0, stream>>>(Of0, Of1, lsF, Oc);

    gemm_proj_kernel<<<dim3(32, 8), 256, 0, stream>>>(
        Oc, wprojb, out, b_proj, 4096, 1024, 1024);
}